// Round 1
// baseline (860.975 us; speedup 1.0000x reference)
//
#include <hip/hip_runtime.h>

#define D 512
#define B 16
#define NNODES 1365
#define OUT_STRIDE (NNODES * D)   // 698880 floats per batch row

// Block = 256 threads. lane mapping: b = tid&15 (16 batch rows), hq = tid>>4
// (16 row-groups). Each thread computes full-D dot products for (b, h) pairs.
// Within a wave (64 lanes = 4 hq-groups x 16 b): W loads have 4 distinct
// addresses x16 same-address lanes (HW broadcast), pa LDS reads have 16
// distinct addresses x4 dup. pa is staged in LDS once per block.
template<int JB>
__global__ __launch_bounds__(256, 3)
void level_kernel(const float* __restrict__ W,
                  const float* __restrict__ bias,
                  const float* __restrict__ src_base,  // inputs (lvl0) or out
                  float* __restrict__ out,
                  int node_start, int slices, int rows_per_block,
                  int src_stride, int is_level0)
{
    __shared__ float pa[B][D + 4];   // +4 pad: spreads b-rows across bank groups

    const int bid   = blockIdx.x;
    const int node  = node_start + bid / slices;
    const int slice = bid % slices;
    const int h0    = slice * rows_per_block;

    const int tid = threadIdx.x;
    const int b   = tid & 15;
    const int hq  = tid >> 4;

    // ---- stage parent activations pa[16][512] into LDS ----
    const float* src = is_level0 ? src_base
                                 : src_base + (size_t)((node - 1) >> 2) * D;
    {
        const int bb  = tid >> 4;   // batch row 0..15
        const int seg = tid & 15;   // float4 lane within row
        const float* srow = src + (size_t)bb * src_stride;
        #pragma unroll
        for (int i = 0; i < 8; ++i) {
            const int d4 = seg + i * 16;            // float4 index 0..127
            float4 v = *reinterpret_cast<const float4*>(srow + d4 * 4);
            *reinterpret_cast<float4*>(&pa[bb][d4 * 4]) = v;
        }
    }
    __syncthreads();

    const int rpt = rows_per_block >> 4;            // rows per thread
    const float* Wn   = W    + (size_t)node * D * D;
    const float* brow = bias + (size_t)node * D;
    float* orow = out + (size_t)b * OUT_STRIDE + (size_t)node * D;
    const int hbase = h0 + hq * rpt;

    for (int j0 = 0; j0 < rpt; j0 += JB) {
        const float* wr[JB];
        float4 acc[JB];
        #pragma unroll
        for (int jj = 0; jj < JB; ++jj) {
            wr[jj]  = Wn + (size_t)(hbase + j0 + jj) * D;
            acc[jj] = make_float4(0.f, 0.f, 0.f, 0.f);
        }

        #pragma unroll 4
        for (int d4 = 0; d4 < D / 4; ++d4) {
            const float4 pv = *reinterpret_cast<const float4*>(&pa[b][d4 * 4]);
            #pragma unroll
            for (int jj = 0; jj < JB; ++jj) {
                const float4 w = *reinterpret_cast<const float4*>(wr[jj] + d4 * 4);
                acc[jj].x += w.x * pv.x;
                acc[jj].y += w.y * pv.y;
                acc[jj].z += w.z * pv.z;
                acc[jj].w += w.w * pv.w;
            }
        }

        #pragma unroll
        for (int jj = 0; jj < JB; ++jj) {
            const int h = hbase + j0 + jj;
            float s = (acc[jj].x + acc[jj].y) + (acc[jj].z + acc[jj].w) + brow[h];
            if (!is_level0) s = fmaxf(s, 0.f);
            orow[h] = s;
        }
    }
}

extern "C" void kernel_launch(void* const* d_in, const int* in_sizes, int n_in,
                              void* d_out, int out_size, void* d_ws, size_t ws_size,
                              hipStream_t stream) {
    const float* inputs = (const float*)d_in[0];   // (16, 512)
    const float* W      = (const float*)d_in[1];   // (1365, 512, 512)
    const float* bias   = (const float*)d_in[2];   // (1365, 512)
    float* out          = (float*)d_out;           // (16, 1365*512)

    const dim3 blk(256);
    // level: (node_start, size, slices, rows_per_block)
    // lvl0:  1 node,  16 slices x 32 rows ->   16 blocks, no relu, src=inputs
    level_kernel<2><<<   1 * 16, blk, 0, stream>>>(W, bias, inputs, out,   0, 16,  32, D, 1);
    // lvl1:  4 nodes, 16 x 32  ->   64 blocks
    level_kernel<2><<<   4 * 16, blk, 0, stream>>>(W, bias, out,    out,   1, 16,  32, OUT_STRIDE, 0);
    // lvl2: 16 nodes, 16 x 32  ->  256 blocks
    level_kernel<2><<<  16 * 16, blk, 0, stream>>>(W, bias, out,    out,   5, 16,  32, OUT_STRIDE, 0);
    // lvl3: 64 nodes,  4 x 128 ->  256 blocks
    level_kernel<8><<<  64 *  4, blk, 0, stream>>>(W, bias, out,    out,  21,  4, 128, OUT_STRIDE, 0);
    // lvl4: 256 nodes, 2 x 256 ->  512 blocks
    level_kernel<8><<< 256 *  2, blk, 0, stream>>>(W, bias, out,    out,  85,  2, 256, OUT_STRIDE, 0);
    // lvl5: 1024 nodes, 1 x 512 -> 1024 blocks
    level_kernel<8><<<1024 *  1, blk, 0, stream>>>(W, bias, out,    out, 341,  1, 512, OUT_STRIDE, 0);
}

// Round 2
// 711.954 us; speedup vs baseline: 1.2093x; 1.2093x over previous
//
#include <hip/hip_runtime.h>

#define D 512
#define NNODES 1365
#define OUT_STRIDE (NNODES * D)   // 698880 floats per batch row

// Lane-owns-row mapping. Each wave covers 64 consecutive W rows (lane = row),
// each lane accumulates all 16 batch outputs for its row(s):
//   acc[b] += W[row][d] * pa[b][d]
// W loads: 64 lanes x distinct 16B (stride 2048B) -> 1KB unique per inst;
// each lane loads 64B contiguous per macro-iter (full line, immediate use).
// pa[b][d] is wave-uniform -> single broadcast ds_read_b128 feeds 4 FMAs of
// the whole wave. pa staged once per block into 32KB LDS.
template<int WAVES, int RPL, bool RELU>
__global__ __launch_bounds__(WAVES * 64, 3)
void lvl_kernel(const float* __restrict__ W,
                const float* __restrict__ bias,
                const float* __restrict__ src_base,   // inputs (lvl0) or out
                float* __restrict__ out,
                int node_start, int slices, int src_stride)
{
    __shared__ float pa[16][D];   // 32 KB

    const int tid   = threadIdx.x;
    const int bid   = blockIdx.x;
    const int node  = node_start + bid / slices;
    const int slice = bid % slices;
    const int wave  = tid >> 6;
    const int lane  = tid & 63;

    // ---- stage parent activations (16 x 512 floats) into LDS ----
    const float* src = RELU ? src_base + (size_t)((node - 1) >> 2) * D
                            : src_base;
    for (int idx = tid; idx < 16 * (D / 4); idx += WAVES * 64) {
        const int b = idx >> 7;          // D/4 = 128 float4 per row
        const int c = idx & 127;
        const float4 v = *reinterpret_cast<const float4*>(
            src + (size_t)b * src_stride + c * 4);
        *reinterpret_cast<float4*>(&pa[b][c * 4]) = v;
    }
    __syncthreads();

    const int rows_per_block = WAVES * 64 * RPL;
    const int row0 = slice * rows_per_block + wave * (64 * RPL) + lane;

    const float* Wn  = W + (size_t)node * D * D;
    const float* wp0 = Wn + (size_t)row0 * D;

    float acc[RPL][16];
    #pragma unroll
    for (int j = 0; j < RPL; ++j)
        #pragma unroll
        for (int b = 0; b < 16; ++b) acc[j][b] = 0.f;

    for (int d16 = 0; d16 < D / 16; ++d16) {
        // load 64B of W per row this lane owns (4 x float4, contiguous)
        float4 w[RPL][4];
        #pragma unroll
        for (int j = 0; j < RPL; ++j) {
            const float* wp = wp0 + (size_t)j * (64 * D) + d16 * 16;
            #pragma unroll
            for (int c = 0; c < 4; ++c)
                w[j][c] = *reinterpret_cast<const float4*>(wp + c * 4);
        }
        // 16 batches x 16 d-values; pa reads are wave-uniform broadcasts
        #pragma unroll
        for (int b = 0; b < 16; ++b) {
            #pragma unroll
            for (int c = 0; c < 4; ++c) {
                const float4 p = *reinterpret_cast<const float4*>(
                    &pa[b][d16 * 16 + c * 4]);
                #pragma unroll
                for (int j = 0; j < RPL; ++j) {
                    acc[j][b] = fmaf(w[j][c].x, p.x, acc[j][b]);
                    acc[j][b] = fmaf(w[j][c].y, p.y, acc[j][b]);
                    acc[j][b] = fmaf(w[j][c].z, p.z, acc[j][b]);
                    acc[j][b] = fmaf(w[j][c].w, p.w, acc[j][b]);
                }
            }
        }
    }

    // ---- epilogue: bias + relu + coalesced stores ----
    const float* brow  = bias + (size_t)node * D;
    float*       obase = out  + (size_t)node * D;
    #pragma unroll
    for (int j = 0; j < RPL; ++j) {
        const int row = row0 + j * 64;
        const float bv = brow[row];
        #pragma unroll
        for (int b = 0; b < 16; ++b) {
            float s = acc[j][b] + bv;
            if (RELU) s = fmaxf(s, 0.f);
            obase[(size_t)b * OUT_STRIDE + row] = s;
        }
    }
}

extern "C" void kernel_launch(void* const* d_in, const int* in_sizes, int n_in,
                              void* d_out, int out_size, void* d_ws, size_t ws_size,
                              hipStream_t stream) {
    const float* inputs = (const float*)d_in[0];   // (16, 512)
    const float* W      = (const float*)d_in[1];   // (1365, 512, 512)
    const float* bias   = (const float*)d_in[2];   // (1365, 512)
    float* out          = (float*)d_out;           // (16, 1365*512)

    // lvl0: 1 node, no relu, src=inputs (row stride 512)
    lvl_kernel<4, 1, false><<<   1 * 2, 256, 0, stream>>>(W, bias, inputs, out,   0, 2, D);
    // lvl1: 4 nodes
    lvl_kernel<4, 1, true ><<<   4 * 2, 256, 0, stream>>>(W, bias, out,    out,   1, 2, OUT_STRIDE);
    // lvl2: 16 nodes
    lvl_kernel<4, 1, true ><<<  16 * 2, 256, 0, stream>>>(W, bias, out,    out,   5, 2, OUT_STRIDE);
    // lvl3: 64 nodes, 128-thread blocks -> 256 blocks (full GPU)
    lvl_kernel<2, 1, true ><<<  64 * 4, 128, 0, stream>>>(W, bias, out,    out,  21, 4, OUT_STRIDE);
    // lvl4: 256 nodes -> 512 blocks
    lvl_kernel<4, 1, true ><<< 256 * 2, 256, 0, stream>>>(W, bias, out,    out,  85, 2, OUT_STRIDE);
    // lvl5: 1024 nodes, 2 rows/lane -> whole node per block, 1024 blocks
    lvl_kernel<4, 2, true ><<<1024 * 1, 256, 0, stream>>>(W, bias, out,    out, 341, 1, OUT_STRIDE);
}

// Round 3
// 546.482 us; speedup vs baseline: 1.5755x; 1.3028x over previous
//
#include <hip/hip_runtime.h>

#define D 512
#define NNODES 1365
#define OUT_STRIDE (NNODES * D)   // 698880 floats per batch row

typedef __attribute__((ext_vector_type(4))) float f32x4;
typedef __attribute__((ext_vector_type(8))) short bf16x8;

union U4 { uint4 q; unsigned u[4]; bf16x8 v; };

// v_cvt_pk_bf16_f32: dst.lo16 = bf16(s0), dst.hi16 = bf16(s1)  (RNE)
__device__ inline unsigned cvt_pk_bf16(float s0, float s1) {
    unsigned r;
    asm volatile("v_cvt_pk_bf16_f32 %0, %1, %2" : "=v"(r) : "v"(s0), "v"(s1));
    return r;
}

__device__ inline void gld_lds16(const void* g, void* l) {
    __builtin_amdgcn_global_load_lds(
        (const __attribute__((address_space(1))) unsigned*)g,
        (__attribute__((address_space(3))) unsigned*)l, 16, 0, 0);
}

// Split-bf16 MFMA GEMM per node: out(16x512) = pa(16x512) @ W^T + bias, relu.
// W streamed LINEARLY (global_load_lds, dbuf 16-row fp32 tiles, XOR-swizzled
// via pre-swizzled global source). Each tile holds full K for 16 W-rows ->
// exactly one 16x16 C-tile; owner wave (t mod 8) computes it alone with
// 16 K-steps x 3 MFMA (Ah*Bh + Al*Bh + Ah*Bl). Counted vmcnt keeps the next
// tile's DMA in flight across raw barriers.
template<bool RELU>
__global__ __launch_bounds__(512)
void node_kernel(const float* __restrict__ W,
                 const float* __restrict__ bias,
                 const float* __restrict__ src_base,   // inputs (lvl0) or out
                 float* __restrict__ out,
                 int node_start, int slices, int rpb, int src_stride)
{
    __shared__ float          Wt[2][16 * 512];    // 64 KB fp32 tile dbuf
    __shared__ unsigned short paH[16 * 512];      // 16 KB pa hi bf16 (swizzled)
    __shared__ unsigned short paL[16 * 512];      // 16 KB pa lo bf16 (swizzled)

    const int tid   = threadIdx.x;
    const int w     = tid >> 6;
    const int lane  = tid & 63;
    const int node  = node_start + blockIdx.x / slices;
    const int slice = blockIdx.x % slices;
    const int row0  = slice * rpb;
    const int NT    = rpb >> 4;

    // ---- stage pa: fp32 -> bf16 hi/lo into swizzled LDS ----
    const float* src = RELU ? src_base + (size_t)((node - 1) >> 2) * D
                            : src_base;
    for (int i = tid; i < 16 * 64; i += 512) {     // 8 elems per item
        const int b  = i >> 6;
        const int c8 = i & 63;
        const float* p = src + (size_t)b * src_stride + c8 * 8;
        float4 x0 = *(const float4*)(p);
        float4 x1 = *(const float4*)(p + 4);
        float xs[8] = {x0.x, x0.y, x0.z, x0.w, x1.x, x1.y, x1.z, x1.w};
        unsigned hi[4], lo[4];
        #pragma unroll
        for (int k = 0; k < 4; ++k) {
            unsigned h = cvt_pk_bf16(xs[2*k], xs[2*k+1]);
            float f0 = __uint_as_float(h << 16);
            float f1 = __uint_as_float(h & 0xFFFF0000u);
            lo[k] = cvt_pk_bf16(xs[2*k] - f0, xs[2*k+1] - f1);
            hi[k] = h;
        }
        const int base = (b * 512 + c8 * 8) * 2;            // byte offset
        const int sw   = base ^ ((b & 7) << 4);             // bank swizzle
        *(uint4*)((char*)paH + sw) = make_uint4(hi[0], hi[1], hi[2], hi[3]);
        *(uint4*)((char*)paL + sw) = make_uint4(lo[0], lo[1], lo[2], lo[3]);
    }
    __syncthreads();

    const float* Wnode = W + (size_t)node * (D * D);

    // stage tile t: 16 rows x 512 fp32 = 32 KB, linear global stream.
    // LDS dest forced linear; swizzle achieved by XOR on the GLOBAL source
    // (involution: bits [6:4] ^= row&7, row = byte>>11).
    auto stage = [&](int t) {
        const int buf = t & 1;
        const char* gbase = (const char*)(Wnode + (size_t)(row0 + t * 16) * D);
        #pragma unroll
        for (int i = 0; i < 4; ++i) {
            const int off  = w * 4096 + i * 1024 + lane * 16;
            const int soff = off ^ (((off >> 11) & 7) << 4);
            gld_lds16(gbase + soff, (char*)Wt[buf] + (w * 4096 + i * 1024));
        }
    };

    stage(0);
    for (int t = 0; t < NT; ++t) {
        if (t + 1 < NT) {
            stage(t + 1);
            asm volatile("s_waitcnt vmcnt(4)" ::: "memory");  // tile t resident
        } else {
            asm volatile("s_waitcnt vmcnt(0)" ::: "memory");
        }
        __builtin_amdgcn_s_barrier();

        if (w == (t & 7)) {
            const int m4 = lane >> 4;      // k-block / C row-group
            const int c0 = lane & 15;      // A row m / B row n / C col
            f32x4 acc = {0.f, 0.f, 0.f, 0.f};
            const char* tb = (const char*)Wt[t & 1];
            const char* ah = (const char*)paH;
            const char* al = (const char*)paL;
            const int rsw = (c0 & 7) << 4;
            #pragma unroll 2
            for (int ks = 0; ks < 16; ++ks) {
                const int kb = ks * 32 + m4 * 8;
                // A frags: pa row c0, k = kb..kb+7 (8 bf16 = 16 B)
                const int ab = ((c0 * 512 + kb) * 2) ^ rsw;
                U4 aH, aL;
                aH.q = *(const uint4*)(ah + ab);
                aL.q = *(const uint4*)(al + ab);
                // B frag: W row c0 (tile-rel), k = kb..kb+7 fp32 -> hi/lo bf16
                const int bb = c0 * 2048 + kb * 4;
                float4 b0 = *(const float4*)(tb + (bb ^ rsw));
                float4 b1 = *(const float4*)(tb + ((bb + 16) ^ rsw));
                U4 bH, bL;
                {
                    float xs[8] = {b0.x, b0.y, b0.z, b0.w, b1.x, b1.y, b1.z, b1.w};
                    #pragma unroll
                    for (int k = 0; k < 4; ++k) {
                        unsigned h = cvt_pk_bf16(xs[2*k], xs[2*k+1]);
                        float f0 = __uint_as_float(h << 16);
                        float f1 = __uint_as_float(h & 0xFFFF0000u);
                        bL.u[k] = cvt_pk_bf16(xs[2*k] - f0, xs[2*k+1] - f1);
                        bH.u[k] = h;
                    }
                }
                acc = __builtin_amdgcn_mfma_f32_16x16x32_bf16(aH.v, bH.v, acc, 0, 0, 0);
                acc = __builtin_amdgcn_mfma_f32_16x16x32_bf16(aL.v, bH.v, acc, 0, 0, 0);
                acc = __builtin_amdgcn_mfma_f32_16x16x32_bf16(aH.v, bL.v, acc, 0, 0, 0);
            }
            // epilogue: C col = lane&15 (W-row n), C row = (lane>>4)*4+i (batch)
            const int wcol = row0 + t * 16 + c0;
            const float bv = bias[(size_t)node * D + wcol];
            float* ob = out + (size_t)node * D + wcol;
            #pragma unroll
            for (int i = 0; i < 4; ++i) {
                const int m = m4 * 4 + i;
                float v = acc[i] + bv;
                if (RELU) v = fmaxf(v, 0.f);
                ob[(size_t)m * OUT_STRIDE] = v;
            }
        }
        __builtin_amdgcn_s_barrier();
    }
}

extern "C" void kernel_launch(void* const* d_in, const int* in_sizes, int n_in,
                              void* d_out, int out_size, void* d_ws, size_t ws_size,
                              hipStream_t stream) {
    const float* inputs = (const float*)d_in[0];   // (16, 512)
    const float* W      = (const float*)d_in[1];   // (1365, 512, 512)
    const float* bias   = (const float*)d_in[2];   // (1365, 512)
    float* out          = (float*)d_out;           // (16, 1365*512)

    const dim3 blk(512);
    // (node_start, slices, rows_per_block)
    node_kernel<false><<<   1 * 16, blk, 0, stream>>>(W, bias, inputs, out,   0, 16,  32, D);
    node_kernel<true ><<<   4 * 16, blk, 0, stream>>>(W, bias, out,    out,   1, 16,  32, OUT_STRIDE);
    node_kernel<true ><<<  16 *  8, blk, 0, stream>>>(W, bias, out,    out,   5,  8,  64, OUT_STRIDE);
    node_kernel<true ><<<  64 *  4, blk, 0, stream>>>(W, bias, out,    out,  21,  4, 128, OUT_STRIDE);
    node_kernel<true ><<< 256 *  2, blk, 0, stream>>>(W, bias, out,    out,  85,  2, 256, OUT_STRIDE);
    node_kernel<true ><<<1024 *  1, blk, 0, stream>>>(W, bias, out,    out, 341,  1, 512, OUT_STRIDE);
}

// Round 4
// 345.541 us; speedup vs baseline: 2.4917x; 1.5815x over previous
//
#include <hip/hip_runtime.h>

#define D 512
#define NNODES 1365
#define OUT_STRIDE (NNODES * D)   // 698880 floats per batch row

typedef __attribute__((ext_vector_type(4))) float f32x4;
typedef __attribute__((ext_vector_type(8))) short bf16x8;

union U4 { uint4 q; unsigned u[4]; bf16x8 v; };

__device__ inline unsigned cvt_pk_bf16(float s0, float s1) {
    unsigned r;
    asm volatile("v_cvt_pk_bf16_f32 %0, %1, %2" : "=v"(r) : "v"(s0), "v"(s1));
    return r;
}

__device__ inline void gld_lds16(const void* g, void* l) {
    __builtin_amdgcn_global_load_lds(
        (const __attribute__((address_space(1))) unsigned*)g,
        (__attribute__((address_space(3))) unsigned*)l, 16, 0, 0);
}

// Barrier-free per-wave streaming GEMM. Block = 4 waves; wave w computes
// 16-row output groups (g*4+w) of its node slice. Per wave: double-buffered
// 8KB chunks (16 rows x 128 K-quarter fp32) DMA'd by global_load_lds with
// counted per-wave vmcnt; pa (A operand) lives in registers as bf16 hi/lo
// frags (split-bf16: 3 MFMA passes). No __syncthreads anywhere.
template<int G, bool RELU>
__global__ __launch_bounds__(256, 2)
void node_kernel(const float* __restrict__ W,
                 const float* __restrict__ bias,
                 const float* __restrict__ src_base,   // inputs (lvl0) or out
                 float* __restrict__ out,
                 int node_start, int bpn, int src_stride)
{
    __shared__ float Wt[4][2][16 * 128];   // 4 waves x 2 bufs x 8 KB = 64 KB

    const int tid  = threadIdx.x;
    const int w    = tid >> 6;
    const int lane = tid & 63;
    const int m4   = lane >> 4;
    const int c0   = lane & 15;

    const int node  = node_start + blockIdx.x / bpn;
    const int nbase = (blockIdx.x % bpn) * (64 * G);   // row base within node

    const float* Wn = W + (size_t)node * (D * D);

    // chunk c = 4g+q: rows nbase+(g*4+w)*16 .. +16, K bytes q*512 .. +512.
    // One inst covers 2 rows (lanes 0-31 row r, 32-63 row r+1); source is
    // XOR-pre-swizzled per row ((r&7)<<4 within 512B), LDS dest linear.
    const int rr  = lane >> 5;
    const int off = (lane & 31) * 16;
    auto issue_chunk = [&](int g, int q) {
        char* ldst = (char*)&Wt[w][(g * 4 + q) & 1][0];
        const char* gsrc = (const char*)Wn +
            (size_t)(nbase + (g * 4 + w) * 16) * 2048 + q * 512;
        #pragma unroll
        for (int i = 0; i < 8; ++i) {
            const int r = i * 2 + rr;
            gld_lds16(gsrc + (size_t)r * 2048 + (off ^ ((r & 7) << 4)),
                      ldst + i * 1024);
        }
    };

    // ---- prologue: bias preload, chunk 0/1 DMA, A-frags into registers ----
    float bv[G];
    #pragma unroll
    for (int g = 0; g < G; ++g) {
        bv[g] = bias[(size_t)node * D + nbase + (g * 4 + w) * 16 + c0];
        asm volatile("" :: "v"(bv[g]));   // force materialization pre-loop
    }

    issue_chunk(0, 0);
    issue_chunk(0, 1);

    // A frags: pa row c0 (batch), k = j*32 + m4*8 + 0..7, j = 0..15
    const float* arow = (RELU ? src_base + (size_t)((node - 1) >> 2) * D
                              : src_base) + (size_t)c0 * src_stride;
    bf16x8 aH[16], aL[16];
    #pragma unroll
    for (int j = 0; j < 16; ++j) {
        const float* p = arow + j * 32 + m4 * 8;
        float4 x0 = *(const float4*)p;
        float4 x1 = *(const float4*)(p + 4);
        float xs[8] = {x0.x,x0.y,x0.z,x0.w,x1.x,x1.y,x1.z,x1.w};
        U4 h, l;
        #pragma unroll
        for (int k = 0; k < 4; ++k) {
            unsigned hh = cvt_pk_bf16(xs[2*k], xs[2*k+1]);
            float f0 = __uint_as_float(hh << 16);
            float f1 = __uint_as_float(hh & 0xFFFF0000u);
            l.u[k] = cvt_pk_bf16(xs[2*k] - f0, xs[2*k+1] - f1);
            h.u[k] = hh;
        }
        aH[j] = h.v; aL[j] = l.v;
    }

    // ---- main: fully unrolled chunk pipeline ----
    f32x4 acc = {0.f, 0.f, 0.f, 0.f};
    #pragma unroll
    for (int g = 0; g < G; ++g) {
        #pragma unroll
        for (int q = 0; q < 4; ++q) {
            // wait for chunk (g,q) resident; never drain mid-stream
            if (q == 0) {
                if (g == 0) asm volatile("s_waitcnt vmcnt(8)"  ::: "memory");
                else        asm volatile("s_waitcnt vmcnt(12)" ::: "memory");
            } else if (q == 3 && g == G - 1) {
                asm volatile("s_waitcnt vmcnt(0)"  ::: "memory");
            } else {
                asm volatile("s_waitcnt vmcnt(8)"  ::: "memory");
            }

            const char* tb = (const char*)&Wt[w][(g * 4 + q) & 1][0];
            const int rsw = (c0 & 7) << 4;
            #pragma unroll
            for (int ks = 0; ks < 4; ++ks) {
                // B frag: row c0, k_local = ks*32 + m4*8 (fp32, swizzled)
                const int kb = ks * 128 + m4 * 32;
                float4 b0 = *(const float4*)(tb + c0 * 512 + (kb ^ rsw));
                float4 b1 = *(const float4*)(tb + c0 * 512 + ((kb + 16) ^ rsw));
                U4 bH, bL;
                float xs[8] = {b0.x,b0.y,b0.z,b0.w,b1.x,b1.y,b1.z,b1.w};
                #pragma unroll
                for (int k = 0; k < 4; ++k) {
                    unsigned hh = cvt_pk_bf16(xs[2*k], xs[2*k+1]);
                    float f0 = __uint_as_float(hh << 16);
                    float f1 = __uint_as_float(hh & 0xFFFF0000u);
                    bL.u[k] = cvt_pk_bf16(xs[2*k] - f0, xs[2*k+1] - f1);
                    bH.u[k] = hh;
                }
                const int j = q * 4 + ks;
                acc = __builtin_amdgcn_mfma_f32_16x16x32_bf16(aH[j], bH.v, acc, 0,0,0);
                acc = __builtin_amdgcn_mfma_f32_16x16x32_bf16(aL[j], bH.v, acc, 0,0,0);
                acc = __builtin_amdgcn_mfma_f32_16x16x32_bf16(aH[j], bL.v, acc, 0,0,0);
            }

            // prefetch chunk c+2 into the buffer just freed
            if (q == 0)      issue_chunk(g, 2);
            else if (q == 1) issue_chunk(g, 3);
            else if (g < G - 1) {
                if (q == 2) issue_chunk(g + 1, 0);
                else        issue_chunk(g + 1, 1);
            }

            // epilogue at end of group: bias + relu + store
            if (q == 3) {
                const int wcol = node * D + nbase + (g * 4 + w) * 16 + c0;
                #pragma unroll
                for (int i = 0; i < 4; ++i) {
                    float v = acc[i] + bv[g];
                    if (RELU) v = fmaxf(v, 0.f);
                    out[(size_t)(m4 * 4 + i) * OUT_STRIDE + wcol] = v;
                }
                acc = (f32x4){0.f, 0.f, 0.f, 0.f};
            }
        }
    }
}

extern "C" void kernel_launch(void* const* d_in, const int* in_sizes, int n_in,
                              void* d_out, int out_size, void* d_ws, size_t ws_size,
                              hipStream_t stream) {
    const float* inputs = (const float*)d_in[0];   // (16, 512)
    const float* W      = (const float*)d_in[1];   // (1365, 512, 512)
    const float* bias   = (const float*)d_in[2];   // (1365, 512)
    float* out          = (float*)d_out;           // (16, 1365*512)

    // (G, RELU) <<<blocks>>> (node_start, blocks_per_node, src_stride)
    node_kernel<1, false><<<   8, 256, 0, stream>>>(W, bias, inputs, out,   0, 8, D);
    node_kernel<1, true ><<<  32, 256, 0, stream>>>(W, bias, out,    out,   1, 8, OUT_STRIDE);
    node_kernel<1, true ><<< 128, 256, 0, stream>>>(W, bias, out,    out,   5, 8, OUT_STRIDE);
    node_kernel<1, true ><<< 512, 256, 0, stream>>>(W, bias, out,    out,  21, 8, OUT_STRIDE);
    node_kernel<4, true ><<< 512, 256, 0, stream>>>(W, bias, out,    out,  85, 2, OUT_STRIDE);
    node_kernel<8, true ><<<1024, 256, 0, stream>>>(W, bias, out,    out, 341, 1, OUT_STRIDE);
}